// Round 9
// baseline (25726.889 us; speedup 1.0000x reference)
//
#include <hip/hip_runtime.h>
#include <hip/hip_fp16.h>

#define T_ 512
#define B_ 128
#define E_ 256
#define H_ 256

typedef _Float16 h8 __attribute__((ext_vector_type(8)));
typedef float    f4 __attribute__((ext_vector_type(4)));
typedef unsigned u4 __attribute__((ext_vector_type(4)));
typedef int      i4 __attribute__((ext_vector_type(4)));

// ---------------------------------------------------------------------------
// workspace layout (bytes) — ends at 37,748,736, the R5-proven-safe extent.
//   wp    (fp16 W frags)                    0   2,097,152
//   uq    (i8 U frags)              2,097,152     524,288
//   scl   (f32 dequant scales)      2,621,440       8,192
//   hfin  (f32 final h)             2,629,632     262,144
//   flags (pdone[16]|cdone[16]|pad) 2,891,776         256
//   zbuf  (fp16 z ring, 2 slots)    4,194,304  33,554,432
// NO allocations past 37,748,736 (R7 post-mortem: probe scratch beyond this
// line corrupted an adjacent live allocation -> absmax 468).
// ---------------------------------------------------------------------------

// K2: fp16 W B-fragment permute (proven, unchanged).
__global__ __launch_bounds__(256) void k_perm(const float* __restrict__ Wf, const float* __restrict__ Uf,
        const float* __restrict__ Wb, const float* __restrict__ Ub, _Float16* __restrict__ wp)
{
    const int bid = blockIdx.x;
    const int d = bid >> 5, mat = (bid >> 4) & 1, p = (bid >> 2) & 3, w = bid & 3;
    const float* src = d ? (mat ? Ub : Wb) : (mat ? Uf : Wf);
    _Float16* dst = wp + (size_t)bid * 16384;
    const int tid = threadIdx.x;
    const int cbase = p * 64 + w * 16;
    __shared__ float S[256][17];
    for (int nt = 0; nt < 4; ++nt) {
        for (int it = 0; it < 16; ++it) {
            int idx = it * 256 + tid;
            int k = idx >> 4, c16 = idx & 15;
            S[k][c16] = src[(size_t)k * 1024 + nt * 256 + cbase + c16];
        }
        __syncthreads();
        for (int it = 0; it < 16; ++it) {
            int idx = it * 256 + tid;
            int k = idx & 255, c16 = idx >> 8;
            dst[(size_t)nt * 4096 + c16 * 256 + k] = (_Float16)S[k][c16];
        }
        __syncthreads();
    }
}

// K2b: i8 U fragments + scales (proven, unchanged).
__global__ __launch_bounds__(256) void k_permU(const float* __restrict__ Uf,
        const float* __restrict__ Ub, char* __restrict__ uq, float* __restrict__ scl)
{
    const int bid = blockIdx.x;          // d*8 + cw
    const int d = bid >> 3;
    const float* U = d ? Ub : Uf;
    const int tid = threadIdx.x;
    if (tid >= 128) return;
    const int nt = tid >> 4, n = tid & 15;
    const int g = nt >> 1, sub = nt & 1;
    const int cw = bid & 7;
    const int col = g * 256 + cw * 32 + sub * 16 + n;
    float mx = 0.f;
    for (int k = 0; k < H_; ++k)
        mx = fmaxf(mx, fabsf(U[(size_t)k * 1024 + col]));
    float su = mx > 0.f ? mx * (1.f / 127.f) : 1.f;
    scl[bid * 128 + tid] = su * (1.f / 127.f);
    float inv = 1.f / su;
    char* dst = uq + (size_t)bid * 32768;
    for (int k = 0; k < H_; ++k) {
        float v = U[(size_t)k * 1024 + col] * inv;
        int qv = (int)__builtin_rintf(v);
        qv = qv > 127 ? 127 : (qv < -127 ? -127 : qv);
        dst[(size_t)((nt * 4 + (k >> 6)) * 64 + ((k >> 4) & 3) * 16 + n) * 16 + (k & 15)] = (char)qv;
    }
}

__device__ __forceinline__ float fsig(float x) {
    float t = __expf(-fabsf(x));
    float r = __builtin_amdgcn_rcpf(1.0f + t);
    return x >= 0.f ? r : 1.0f - r;
}
__device__ __forceinline__ float ftanh(float x) {
    float t = __expf(-2.0f * fabsf(x));
    float r = (1.0f - t) * __builtin_amdgcn_rcpf(1.0f + t);
    return x >= 0.f ? r : -r;
}

// ---------------------------------------------------------------------------
// ZERO-FOOTPRINT PROBES. Results exported via each probe's OWN dur_us in the
// rocprof table (no bulk writes; 4-byte DCE-keeper into flags pad, which is
// memset-zeroed before k_fused and never read by it).
// DECODE:
//   clk(GHz)   = 9600 / dur_us(p_clk)            [9.6M dependent-FMA cycles]
//   step_cy    = dur_us(p_X) * 1000 * clk / 3072
//   p_mfba/p_full missing from top-5  =>  dur < ~2ms  =>  step < ~1.6K cy.
// ---------------------------------------------------------------------------
__global__ __launch_bounds__(512, 1) void p_clk(unsigned* __restrict__ outw)
{
    float a = (float)threadIdx.x * 1e-8f + 1.0f;
    const float b = 1.0000001f, cc = 1e-9f;
    #pragma unroll 1
    for (int i = 0; i < 600000; ++i) {      // 2.4M dependent FMAs = 9.6M cy
        a = __builtin_fmaf(a, b, cc);
        a = __builtin_fmaf(a, b, cc);
        a = __builtin_fmaf(a, b, cc);
        a = __builtin_fmaf(a, b, cc);
    }
    if (blockIdx.x == 0 && threadIdx.x == 0)
        outw[40] = __builtin_bit_cast(unsigned, a);
}

__global__ __launch_bounds__(512, 1) void p_mfba(const char* __restrict__ uq,
        unsigned* __restrict__ outw)
{
    const int bid = blockIdx.x;
    const int tid = threadIdx.x;
    const int lane = tid & 63;
    const int l16 = lane & 15, q = lane >> 4;
    const int cw = tid >> 6;
    __shared__ char hbuf[2][1024];
    ((int*)hbuf)[tid] = ((const int*)uq)[tid & 255] ^ (int)(tid * 2654435761u);
    i4 uw[8][4];
    {
        const char* ub = uq + (size_t)((bid & 1) * 8 + cw) * 32768;
        #pragma unroll
        for (int nt = 0; nt < 8; ++nt)
            #pragma unroll
            for (int kb = 0; kb < 4; ++kb)
                uw[nt][kb] = *(const i4*)(ub + (size_t)((nt * 4 + kb) * 64 + lane) * 16);
        #pragma unroll
        for (int nt = 0; nt < 8; ++nt)
            #pragma unroll
            for (int kb = 0; kb < 4; ++kb)
                asm volatile("" : "+v"(uw[nt][kb]));
    }
    __syncthreads();
    i4 acc[8];
    #pragma unroll
    for (int nt = 0; nt < 8; ++nt) acc[nt] = (i4){0, 0, 0, 0};
    #pragma unroll 1
    for (int s = 0; s < 3072; ++s) {
        const char* hb = hbuf[s & 1];
        i4 hf[4];
        #pragma unroll
        for (int kb = 0; kb < 4; ++kb)
            hf[kb] = *(const i4*)(hb + (kb * 4 + q) * 64 + (l16 & 3) * 16);
        #pragma unroll
        for (int kb = 0; kb < 4; ++kb)
            #pragma unroll
            for (int nt = 0; nt < 8; ++nt)
                acc[nt] = __builtin_amdgcn_mfma_i32_16x16x64_i8(hf[kb], uw[nt][kb], acc[nt], 0, 0, 0);
        asm volatile("s_waitcnt lgkmcnt(0)\n\ts_barrier" ::: "memory");
    }
    #pragma unroll
    for (int nt = 0; nt < 8; ++nt) asm volatile("" :: "v"(acc[nt]));   // keep-alive
    if (bid == 0 && tid == 0)
        outw[44] = (unsigned)acc[0][0];
}

__global__ __launch_bounds__(512, 1) void p_full(const char* __restrict__ uq,
        const float* __restrict__ scl, unsigned* __restrict__ outw)
{
    const int bid = blockIdx.x;
    const int tid = threadIdx.x;
    const int lane = tid & 63;
    const int l16 = lane & 15, q = lane >> 4;
    const int cw = tid >> 6;
    const int sub = q >> 1;
    const int rhi = q & 1;
    const int rlo = rhi * 2;
    __shared__ char hbuf[2][1024];
    ((int*)hbuf)[tid] = ((const int*)uq)[tid & 255] ^ (int)(tid * 2654435761u);
    i4 uw[8][4];
    {
        const char* ub = uq + (size_t)((bid & 1) * 8 + cw) * 32768;
        #pragma unroll
        for (int nt = 0; nt < 8; ++nt)
            #pragma unroll
            for (int kb = 0; kb < 4; ++kb)
                uw[nt][kb] = *(const i4*)(ub + (size_t)((nt * 4 + kb) * 64 + lane) * 16);
        #pragma unroll
        for (int nt = 0; nt < 8; ++nt)
            #pragma unroll
            for (int kb = 0; kb < 4; ++kb)
                asm volatile("" : "+v"(uw[nt][kb]));
    }
    float sclv[4];
    #pragma unroll
    for (int g = 0; g < 4; ++g)
        sclv[g] = scl[((bid & 1) * 8 + cw) * 128 + (g * 2 + sub) * 16 + l16];
    u4 X = *(const u4*)(uq + ((size_t)tid * 16 & 32767));
    float c2[2] = {0.f, 0.f}, h2[2] = {0.f, 0.f};
    __syncthreads();
    #pragma unroll 1
    for (int s = 0; s < 3072; ++s) {
        i4 acc[8];
        #pragma unroll
        for (int nt = 0; nt < 8; ++nt) acc[nt] = (i4){0, 0, 0, 0};
        const char* hb = hbuf[s & 1];
        i4 hf[4];
        #pragma unroll
        for (int kb = 0; kb < 4; ++kb)
            hf[kb] = *(const i4*)(hb + (kb * 4 + q) * 64 + (l16 & 3) * 16);
        #pragma unroll
        for (int kb = 0; kb < 4; ++kb)
            #pragma unroll
            for (int nt = 0; nt < 8; ++nt)
                acc[nt] = __builtin_amdgcn_mfma_i32_16x16x64_i8(hf[kb], uw[nt][kb], acc[nt], 0, 0, 0);
        h8 xh = __builtin_bit_cast(h8, X);
        char* hbw = hbuf[(s + 1) & 1];
        float zg4[4][2];
        #pragma unroll
        for (int g = 0; g < 4; ++g) {
            i4 as = sub ? acc[g * 2 + 1] : acc[g * 2];
            f4 fa = {(float)as[0], (float)as[1], (float)as[2], (float)as[3]};
            float za = rhi ? fa[2] : fa[0];
            float zbv = rhi ? fa[3] : fa[1];
            zg4[g][0] = za * sclv[g] + (float)xh[g * 2 + 0];
            zg4[g][1] = zbv * sclv[g] + (float)xh[g * 2 + 1];
        }
        #pragma unroll
        for (int r2 = 0; r2 < 2; ++r2) {
            float cn = fsig(zg4[1][r2]) * c2[r2] + fsig(zg4[0][r2]) * ftanh(zg4[2][r2]);
            c2[r2] = cn;
            float hv = fsig(zg4[3][r2]) * ftanh(cn);
            h2[r2] = hv;
            int hq = (int)__builtin_rintf(hv * 127.f);
            hbw[(cw * 2 + sub) * 64 + (rlo + r2) * 16 + l16] = (char)hq;
        }
        asm volatile("s_waitcnt lgkmcnt(0)\n\ts_barrier" ::: "memory");
    }
    asm volatile("" :: "v"(h2[0]), "v"(h2[1]), "v"(c2[0]), "v"(c2[1]));  // keep-alive
    if (bid == 0 && tid == 0)
        outw[48] = __builtin_bit_cast(unsigned, h2[0]);
}

// ---------------------------------------------------------------------------
// K3 fused persistent kernel (R5 structure + release/acquire fences).
// ---------------------------------------------------------------------------
__global__ __launch_bounds__(512, 1) void k_fused(
        const int* __restrict__ tok, const float* __restrict__ emb,
        const _Float16* __restrict__ wp, const char* __restrict__ uq,
        const float* __restrict__ scl, const float* __restrict__ bf,
        const float* __restrict__ bb, _Float16* __restrict__ zbuf,
        unsigned* __restrict__ pdone, unsigned* __restrict__ cdone,
        float* __restrict__ hfin)
{
    const int bid = blockIdx.x;
    const int tid = threadIdx.x;
    const int lane = tid & 63;
    const int l16 = lane & 15, q = lane >> 4;

    __shared__ int rows[B_];
    __shared__ h8 xle[64 * 64];          // 64 KB producer staging
    __shared__ char hbuf[2][1024];       // consumer h exchange

    if (bid < 64) {
        // ================= consumer =================
        const int d = bid >> 5, qgrp = bid & 31;
        const int cw = tid >> 6;
        const int sub = q >> 1;
        const int rhi = q & 1;
        const int rlo = rhi * 2;

        i4 uw[8][4];
        {
            const char* ub = uq + (size_t)(d * 8 + cw) * 32768;
            #pragma unroll
            for (int nt = 0; nt < 8; ++nt)
                #pragma unroll
                for (int kb = 0; kb < 4; ++kb)
                    uw[nt][kb] = *(const i4*)(ub + (size_t)((nt * 4 + kb) * 64 + lane) * 16);
            #pragma unroll
            for (int nt = 0; nt < 8; ++nt)
                #pragma unroll
                for (int kb = 0; kb < 4; ++kb)
                    asm volatile("" : "+v"(uw[nt][kb]));
        }
        float sclv[4];
        #pragma unroll
        for (int g = 0; g < 4; ++g)
            sclv[g] = scl[(d * 8 + cw) * 128 + (g * 2 + sub) * 16 + l16];

        float c2[2] = {0.f, 0.f}, h2[2] = {0.f, 0.f};
        const _Float16* zb = zbuf + ((((size_t)d * 32 + qgrp) * 8 + cw) * 64 + lane) * 8;
        u4 xwA, xwB, xwC, xwD;

#define ZLD(X, SB, SL) { int sl_ = (SL); if (sl_ > 31) sl_ = 31;                 \
    const _Float16* zp_ = (SB) + (size_t)sl_ * 262144;                           \
    asm volatile("global_load_dwordx4 %0, %1, off sc0 sc1" : "=v"(X) : "v"(zp_) : "memory"); }

#define STEP(X, I)                                                               \
    {                                                                            \
        const int s_ = c * 32 + (I);                                             \
        i4 acc[8];                                                               \
        _Pragma("unroll")                                                        \
        for (int nt = 0; nt < 8; ++nt) acc[nt] = (i4){0, 0, 0, 0};               \
        if (s_ > 0) {                                                            \
            const char* hb = hbuf[(s_ - 1) & 1];                                 \
            i4 hf[4];                                                            \
            _Pragma("unroll")                                                    \
            for (int kb = 0; kb < 4; ++kb)                                       \
                hf[kb] = *(const i4*)(hb + (kb * 4 + q) * 64 + (l16 & 3) * 16);  \
            _Pragma("unroll")                                                    \
            for (int kb = 0; kb < 4; ++kb)                                       \
                _Pragma("unroll")                                                \
                for (int nt = 0; nt < 8; ++nt)                                   \
                    acc[nt] = __builtin_amdgcn_mfma_i32_16x16x64_i8(hf[kb], uw[nt][kb], acc[nt], 0, 0, 0); \
        }                                                                        \
        asm volatile("s_waitcnt vmcnt(3)" : "+v"(X) :: "memory");                \
        h8 xh = __builtin_bit_cast(h8, X);                                       \
        ZLD(X, sb, (I) + 4);                                                     \
        char* hbw = hbuf[s_ & 1];                                                \
        float zg4[4][2];                                                         \
        _Pragma("unroll")                                                        \
        for (int g = 0; g < 4; ++g) {                                            \
            i4 as = sub ? acc[g * 2 + 1] : acc[g * 2];                           \
            f4 fa = {(float)as[0], (float)as[1], (float)as[2], (float)as[3]};    \
            float za = rhi ? fa[2] : fa[0];                                      \
            float zbv = rhi ? fa[3] : fa[1];                                     \
            zg4[g][0] = za * sclv[g] + (float)xh[g * 2 + 0];                     \
            zg4[g][1] = zbv * sclv[g] + (float)xh[g * 2 + 1];                    \
        }                                                                        \
        _Pragma("unroll")                                                        \
        for (int r2 = 0; r2 < 2; ++r2) {                                         \
            float cn = fsig(zg4[1][r2]) * c2[r2] + fsig(zg4[0][r2]) * ftanh(zg4[2][r2]); \
            c2[r2] = cn;                                                         \
            float hv = fsig(zg4[3][r2]) * ftanh(cn);                             \
            h2[r2] = hv;                                                         \
            int hq = (int)__builtin_rintf(hv * 127.f);                           \
            hbw[(cw * 2 + sub) * 64 + (rlo + r2) * 16 + l16] = (char)hq;         \
        }                                                                        \
        asm volatile("s_waitcnt lgkmcnt(0)\n\ts_barrier" ::: "memory");          \
    }

        for (int c = 0; c < 16; ++c) {
            if (tid == 0) {
                const unsigned* fp = pdone + c;
                unsigned v;
                while (true) {
                    asm volatile("global_load_dword %0, %1, off sc0 sc1" : "=v"(v) : "v"(fp) : "memory");
                    asm volatile("s_waitcnt vmcnt(0)" : "+v"(v) :: "memory");
                    if (v == 64u) break;
                    __builtin_amdgcn_s_sleep(16);
                }
                __threadfence();             // ACQUIRE
            }
            __syncthreads();
            asm volatile("s_waitcnt vmcnt(0)" ::: "memory");
            const _Float16* sb = zb + (size_t)(c & 1) * 8388608;
            ZLD(xwA, sb, 0); ZLD(xwB, sb, 1); ZLD(xwC, sb, 2); ZLD(xwD, sb, 3);
            for (int i = 0; i < 32; i += 4) {
                STEP(xwA, i);
                STEP(xwB, i + 1);
                STEP(xwC, i + 2);
                STEP(xwD, i + 3);
            }
            if (tid == 0) atomicAdd(cdone + c, 1u);
        }
#undef STEP
#undef ZLD
        #pragma unroll
        for (int r2 = 0; r2 < 2; ++r2) {
            int b = qgrp * 4 + rlo + r2;
            int unit = cw * 32 + sub * 16 + l16;
            hfin[((size_t)d * B_ + b) * H_ + unit] = h2[r2];
        }
    } else {
        // ================= producer =================
        const int pid = bid - 64;        // 0..191
        const int w8 = tid >> 6, ph = w8 >> 2, w4 = w8 & 3;
        for (int j = pid; j < 1024; j += 192) {
            const int c = j >> 6, t = j & 63;
            const int sl = t >> 1, d = t & 1;
            const int s = c * 32 + sl;
            if (c >= 2 && tid == 0) {
                const unsigned* fp = cdone + (c - 2);
                unsigned v;
                while (true) {
                    asm volatile("global_load_dword %0, %1, off sc0 sc1" : "=v"(v) : "v"(fp) : "memory");
                    asm volatile("s_waitcnt vmcnt(0)" : "+v"(v) :: "memory");
                    if (v == 64u) break;
                    __builtin_amdgcn_s_sleep(16);
                }
            }
            __syncthreads();
            const int tt = d ? (T_ - 1 - s) : s;
            if (tid < B_) rows[tid] = tok[(size_t)tid * T_ + tt];
            __syncthreads();
            for (int it = 0; it < 8; ++it) {
                int pair = it * 8 + w8;      // pair = g8*8 + kb
                int g8 = pair >> 3, kb = pair & 7;
                int b = g8 * 16 + l16;
                int e = kb * 32 + q * 8;
                const float* src = emb + (size_t)rows[b] * E_ + e;
                float4 a = *(const float4*)src;
                float4 cc = *(const float4*)(src + 4);
                h8 hv;
                hv[0] = (_Float16)a.x;  hv[1] = (_Float16)a.y;  hv[2] = (_Float16)a.z;  hv[3] = (_Float16)a.w;
                hv[4] = (_Float16)cc.x; hv[5] = (_Float16)cc.y; hv[6] = (_Float16)cc.z; hv[7] = (_Float16)cc.w;
                xle[pair * 64 + lane] = hv;
            }
            __syncthreads();
            const float* bias = d ? bb : bf;
            _Float16* zslot = zbuf + (size_t)(c & 1) * 8388608;
            for (int pi = 0; pi < 2; ++pi) {
                const int p = ph * 2 + pi;
                const _Float16* bx = wp + (size_t)(d * 32 + p * 4 + w4) * 16384;
                h8 wb[4][8];
                #pragma unroll
                for (int nt = 0; nt < 4; ++nt)
                    #pragma unroll
                    for (int kb = 0; kb < 8; ++kb)
                        wb[nt][kb] = *(const h8*)(bx + nt * 4096 + l16 * 256 + kb * 32 + q * 8);
                float bvv[4];
                #pragma unroll
                for (int nt = 0; nt < 4; ++nt)
                    bvv[nt] = bias[nt * 256 + p * 64 + w4 * 16 + l16];
                for (int g8 = 0; g8 < 8; ++g8) {
                    h8 xa[8];
                    #pragma unroll
                    for (int kb = 0; kb < 8; ++kb)
                        xa[kb] = xle[(g8 * 8 + kb) * 64 + lane];
                    f4 acc[4];
                    #pragma unroll
                    for (int nt = 0; nt < 4; ++nt)
                        acc[nt] = (f4){bvv[nt], bvv[nt], bvv[nt], bvv[nt]};
                    #pragma unroll
                    for (int kb = 0; kb < 8; ++kb)
                        #pragma unroll
                        for (int nt = 0; nt < 4; ++nt)
                            acc[nt] = __builtin_amdgcn_mfma_f32_16x16x32_f16(xa[kb], wb[nt][kb], acc[nt], 0, 0, 0);
                    size_t base = (((size_t)(sl * 2 + d) * 32 + (g8 * 4 + q)) * 8
                                   + (p * 2 + (w4 >> 1))) * 64;
                    #pragma unroll
                    for (int k = 0; k < 2; ++k) {
                        u4 pk;
                        #pragma unroll
                        for (int g = 0; g < 4; ++g) {
                            _Float16 e0 = (_Float16)acc[g][2 * k];
                            _Float16 e1 = (_Float16)acc[g][2 * k + 1];
                            pk[g] = (unsigned)__builtin_bit_cast(unsigned short, e0)
                                  | ((unsigned)__builtin_bit_cast(unsigned short, e1) << 16);
                        }
                        _Float16* da = zslot + (base + ((w4 & 1) * 2 + k) * 16 + l16) * 8;
                        asm volatile("global_store_dwordx4 %0, %1, off sc0 sc1" :: "v"(da), "v"(pk) : "memory");
                    }
                }
            }
            asm volatile("s_waitcnt vmcnt(0)" ::: "memory");
            __syncthreads();               // all 8 waves' stores issued+acked
            if (tid == 0) {
                __threadfence();           // RELEASE
                atomicAdd(pdone + c, 1u);
            }
        }
    }
}

// K4: head (proven, unchanged).
__global__ __launch_bounds__(256) void k_head(const float* __restrict__ hfin,
        const float* __restrict__ W1, const float* __restrict__ b1,
        const float* __restrict__ W2, const float* __restrict__ b2, float* __restrict__ out)
{
    const int b = blockIdx.x;
    const int tid = threadIdx.x;
    __shared__ float hcat[2 * H_];
    __shared__ float a1[256];
    if (tid < 128) {
        if (tid < 64)
            ((float4*)hcat)[tid] = ((const float4*)(hfin + (size_t)b * H_))[tid];
        else
            ((float4*)(hcat + H_))[tid - 64] = ((const float4*)(hfin + (size_t)(B_ + b) * H_))[tid - 64];
    }
    __syncthreads();
    {
        float s = b1[tid];
        #pragma unroll 4
        for (int k = 0; k < 2 * H_; ++k)
            s += hcat[k] * W1[(size_t)k * 256 + tid];
        a1[tid] = s > 0.f ? s : 0.f;
    }
    __syncthreads();
    if (tid < 32) {
        float s = b2[tid];
        #pragma unroll 4
        for (int j = 0; j < 256; ++j)
            s += a1[j] * W2[(size_t)j * 32 + tid];
        float mx = s;
        #pragma unroll
        for (int o = 16; o > 0; o >>= 1)
            mx = fmaxf(mx, __shfl_xor(mx, o, 32));
        float e = __expf(s - mx);
        float sum = e;
        #pragma unroll
        for (int o = 16; o > 0; o >>= 1)
            sum += __shfl_xor(sum, o, 32);
        out[(size_t)b * 32 + tid] = e / sum;
    }
}

// ---------------------------------------------------------------------------
extern "C" void kernel_launch(void* const* d_in, const int* in_sizes, int n_in,
                              void* d_out, int out_size, void* d_ws, size_t ws_size,
                              hipStream_t stream)
{
    (void)in_sizes; (void)n_in; (void)out_size; (void)ws_size;
    const int*   tok = (const int*)d_in[0];
    const float* emb = (const float*)d_in[1];
    const float* Wf  = (const float*)d_in[2];
    const float* Uf  = (const float*)d_in[3];
    const float* bf  = (const float*)d_in[4];
    const float* Wb  = (const float*)d_in[5];
    const float* Ub  = (const float*)d_in[6];
    const float* bb  = (const float*)d_in[7];
    const float* W1  = (const float*)d_in[8];
    const float* b1  = (const float*)d_in[9];
    const float* W2  = (const float*)d_in[10];
    const float* b2  = (const float*)d_in[11];
    float* out = (float*)d_out;

    char* ws = (char*)d_ws;
    _Float16* wp    = (_Float16*)(ws);               //  2,097,152 B
    char*     uqp   = (char*)    (ws + 2097152);     //    524,288 B
    float*    scl   = (float*)   (ws + 2621440);     //      8,192 B
    float*    hfin  = (float*)   (ws + 2629632);     //    262,144 B
    unsigned* flags = (unsigned*)(ws + 2891776);     //        256 B (probe pad at +160)
    _Float16* zbuf  = (_Float16*)(ws + 4194304);     // 33,554,432 B (2-slot ring)

    k_perm <<<64, 256, 0, stream>>>(Wf, Uf, Wb, Ub, wp);
    k_permU<<<16, 256, 0, stream>>>(Uf, Ub, uqp, scl);
    // Zero-footprint diagnostic probes: results read from their dur_us rows.
    p_clk <<<64, 512, 0, stream>>>(flags);
    p_mfba<<<64, 512, 0, stream>>>(uqp, flags);
    p_full<<<64, 512, 0, stream>>>(uqp, scl, flags);
    // memset AFTER probes: zeroes handshake flags (and probe pad) every launch.
    hipMemsetAsync(flags, 0, 256, stream);
    k_fused<<<256, 512, 0, stream>>>(tok, emb, wp, uqp, scl, bf, bb,
                                     zbuf, flags, flags + 16, hfin);
    k_head <<<B_, 256, 0, stream>>>(hfin, W1, b1, W2, b2, out);
}

// Round 10
// 2279.696 us; speedup vs baseline: 11.2852x; 11.2852x over previous
//
#include <hip/hip_runtime.h>
#include <hip/hip_fp16.h>

#define T_ 512
#define B_ 128
#define E_ 256
#define H_ 256

typedef _Float16 h8 __attribute__((ext_vector_type(8)));
typedef float    f4 __attribute__((ext_vector_type(4)));
typedef unsigned u4 __attribute__((ext_vector_type(4)));
typedef int      i4 __attribute__((ext_vector_type(4)));

// ---------------------------------------------------------------------------
// workspace layout (bytes) — ends at 37,748,736, the R5-proven-safe extent.
//   wp    (fp16 W frags)                    0   2,097,152
//   uq    (i8 U frags)              2,097,152     524,288
//   scl   (f32 dequant scales)      2,621,440       8,192
//   hfin  (f32 final h)             2,629,632     262,144
//   flags (pdone[16]|cdone[16]|pad) 2,891,776         256
//   zbuf  (fp16 z ring, 2 slots)    4,194,304  33,554,432
// R9 probe verdict: chip runs at ~0.79 GHz under this workload (p_clk decode
// 9600/12093µs), 1/3 of max — the consumer step is ~3,100 REAL cycles, near
// the analytic chain. v10 single change: producers become MFMA heaters while
// idle, to pull the DVFS governor up to GEMM-class clocks.
// ---------------------------------------------------------------------------

// K2: fp16 W B-fragment permute (proven, unchanged).
__global__ __launch_bounds__(256) void k_perm(const float* __restrict__ Wf, const float* __restrict__ Uf,
        const float* __restrict__ Wb, const float* __restrict__ Ub, _Float16* __restrict__ wp)
{
    const int bid = blockIdx.x;
    const int d = bid >> 5, mat = (bid >> 4) & 1, p = (bid >> 2) & 3, w = bid & 3;
    const float* src = d ? (mat ? Ub : Wb) : (mat ? Uf : Wf);
    _Float16* dst = wp + (size_t)bid * 16384;
    const int tid = threadIdx.x;
    const int cbase = p * 64 + w * 16;
    __shared__ float S[256][17];
    for (int nt = 0; nt < 4; ++nt) {
        for (int it = 0; it < 16; ++it) {
            int idx = it * 256 + tid;
            int k = idx >> 4, c16 = idx & 15;
            S[k][c16] = src[(size_t)k * 1024 + nt * 256 + cbase + c16];
        }
        __syncthreads();
        for (int it = 0; it < 16; ++it) {
            int idx = it * 256 + tid;
            int k = idx & 255, c16 = idx >> 8;
            dst[(size_t)nt * 4096 + c16 * 256 + k] = (_Float16)S[k][c16];
        }
        __syncthreads();
    }
}

// K2b: i8 U fragments + scales (proven, unchanged).
__global__ __launch_bounds__(256) void k_permU(const float* __restrict__ Uf,
        const float* __restrict__ Ub, char* __restrict__ uq, float* __restrict__ scl)
{
    const int bid = blockIdx.x;          // d*8 + cw
    const int d = bid >> 3;
    const float* U = d ? Ub : Uf;
    const int tid = threadIdx.x;
    if (tid >= 128) return;
    const int nt = tid >> 4, n = tid & 15;
    const int g = nt >> 1, sub = nt & 1;
    const int cw = bid & 7;
    const int col = g * 256 + cw * 32 + sub * 16 + n;
    float mx = 0.f;
    for (int k = 0; k < H_; ++k)
        mx = fmaxf(mx, fabsf(U[(size_t)k * 1024 + col]));
    float su = mx > 0.f ? mx * (1.f / 127.f) : 1.f;
    scl[bid * 128 + tid] = su * (1.f / 127.f);
    float inv = 1.f / su;
    char* dst = uq + (size_t)bid * 32768;
    for (int k = 0; k < H_; ++k) {
        float v = U[(size_t)k * 1024 + col] * inv;
        int qv = (int)__builtin_rintf(v);
        qv = qv > 127 ? 127 : (qv < -127 ? -127 : qv);
        dst[(size_t)((nt * 4 + (k >> 6)) * 64 + ((k >> 4) & 3) * 16 + n) * 16 + (k & 15)] = (char)qv;
    }
}

__device__ __forceinline__ float fsig(float x) {
    float t = __expf(-fabsf(x));
    float r = __builtin_amdgcn_rcpf(1.0f + t);
    return x >= 0.f ? r : 1.0f - r;
}
__device__ __forceinline__ float ftanh(float x) {
    float t = __expf(-2.0f * fabsf(x));
    float r = (1.0f - t) * __builtin_amdgcn_rcpf(1.0f + t);
    return x >= 0.f ? r : -r;
}

// ---------------------------------------------------------------------------
// K3 fused persistent kernel. Consumers: R5+fences structure (proven,
// absmax 2.44e-4). Producers: tiles as before, but every wait becomes a
// dense-MFMA heater burst (DVFS ramp) with WG-level polling.
// ---------------------------------------------------------------------------
__global__ __launch_bounds__(512, 1) void k_fused(
        const int* __restrict__ tok, const float* __restrict__ emb,
        const _Float16* __restrict__ wp, const char* __restrict__ uq,
        const float* __restrict__ scl, const float* __restrict__ bf,
        const float* __restrict__ bb, _Float16* __restrict__ zbuf,
        unsigned* __restrict__ pdone, unsigned* __restrict__ cdone,
        float* __restrict__ hfin)
{
    const int bid = blockIdx.x;
    const int tid = threadIdx.x;
    const int lane = tid & 63;
    const int l16 = lane & 15, q = lane >> 4;

    __shared__ int rows[B_];
    __shared__ h8 xle[64 * 64];          // 64 KB producer staging
    __shared__ char hbuf[2][1024];       // consumer h exchange
    __shared__ unsigned hflag;           // heater exit broadcast

    if (bid < 64) {
        // ================= consumer =================
        const int d = bid >> 5, qgrp = bid & 31;
        const int cw = tid >> 6;
        const int sub = q >> 1;
        const int rhi = q & 1;
        const int rlo = rhi * 2;

        i4 uw[8][4];
        {
            const char* ub = uq + (size_t)(d * 8 + cw) * 32768;
            #pragma unroll
            for (int nt = 0; nt < 8; ++nt)
                #pragma unroll
                for (int kb = 0; kb < 4; ++kb)
                    uw[nt][kb] = *(const i4*)(ub + (size_t)((nt * 4 + kb) * 64 + lane) * 16);
            #pragma unroll
            for (int nt = 0; nt < 8; ++nt)
                #pragma unroll
                for (int kb = 0; kb < 4; ++kb)
                    asm volatile("" : "+v"(uw[nt][kb]));
        }
        float sclv[4];
        #pragma unroll
        for (int g = 0; g < 4; ++g)
            sclv[g] = scl[(d * 8 + cw) * 128 + (g * 2 + sub) * 16 + l16];

        float c2[2] = {0.f, 0.f}, h2[2] = {0.f, 0.f};
        const _Float16* zb = zbuf + ((((size_t)d * 32 + qgrp) * 8 + cw) * 64 + lane) * 8;
        u4 xwA, xwB, xwC, xwD;

#define ZLD(X, SB, SL) { int sl_ = (SL); if (sl_ > 31) sl_ = 31;                 \
    const _Float16* zp_ = (SB) + (size_t)sl_ * 262144;                           \
    asm volatile("global_load_dwordx4 %0, %1, off sc0 sc1" : "=v"(X) : "v"(zp_) : "memory"); }

#define STEP(X, I)                                                               \
    {                                                                            \
        const int s_ = c * 32 + (I);                                             \
        i4 acc[8];                                                               \
        _Pragma("unroll")                                                        \
        for (int nt = 0; nt < 8; ++nt) acc[nt] = (i4){0, 0, 0, 0};               \
        if (s_ > 0) {                                                            \
            const char* hb = hbuf[(s_ - 1) & 1];                                 \
            i4 hf[4];                                                            \
            _Pragma("unroll")                                                    \
            for (int kb = 0; kb < 4; ++kb)                                       \
                hf[kb] = *(const i4*)(hb + (kb * 4 + q) * 64 + (l16 & 3) * 16);  \
            _Pragma("unroll")                                                    \
            for (int kb = 0; kb < 4; ++kb)                                       \
                _Pragma("unroll")                                                \
                for (int nt = 0; nt < 8; ++nt)                                   \
                    acc[nt] = __builtin_amdgcn_mfma_i32_16x16x64_i8(hf[kb], uw[nt][kb], acc[nt], 0, 0, 0); \
        }                                                                        \
        asm volatile("s_waitcnt vmcnt(3)" : "+v"(X) :: "memory");                \
        h8 xh = __builtin_bit_cast(h8, X);                                       \
        ZLD(X, sb, (I) + 4);                                                     \
        char* hbw = hbuf[s_ & 1];                                                \
        float zg4[4][2];                                                         \
        _Pragma("unroll")                                                        \
        for (int g = 0; g < 4; ++g) {                                            \
            i4 as = sub ? acc[g * 2 + 1] : acc[g * 2];                           \
            f4 fa = {(float)as[0], (float)as[1], (float)as[2], (float)as[3]};    \
            float za = rhi ? fa[2] : fa[0];                                      \
            float zbv = rhi ? fa[3] : fa[1];                                     \
            zg4[g][0] = za * sclv[g] + (float)xh[g * 2 + 0];                     \
            zg4[g][1] = zbv * sclv[g] + (float)xh[g * 2 + 1];                    \
        }                                                                        \
        _Pragma("unroll")                                                        \
        for (int r2 = 0; r2 < 2; ++r2) {                                         \
            float cn = fsig(zg4[1][r2]) * c2[r2] + fsig(zg4[0][r2]) * ftanh(zg4[2][r2]); \
            c2[r2] = cn;                                                         \
            float hv = fsig(zg4[3][r2]) * ftanh(cn);                             \
            h2[r2] = hv;                                                         \
            int hq = (int)__builtin_rintf(hv * 127.f);                           \
            hbw[(cw * 2 + sub) * 64 + (rlo + r2) * 16 + l16] = (char)hq;         \
        }                                                                        \
        asm volatile("s_waitcnt lgkmcnt(0)\n\ts_barrier" ::: "memory");          \
    }

        for (int c = 0; c < 16; ++c) {
            if (tid == 0) {
                const unsigned* fp = pdone + c;
                unsigned v;
                while (true) {
                    asm volatile("global_load_dword %0, %1, off sc0 sc1" : "=v"(v) : "v"(fp) : "memory");
                    asm volatile("s_waitcnt vmcnt(0)" : "+v"(v) :: "memory");
                    if (v == 64u) break;
                    __builtin_amdgcn_s_sleep(16);
                }
                __threadfence();             // ACQUIRE
            }
            __syncthreads();
            asm volatile("s_waitcnt vmcnt(0)" ::: "memory");
            const _Float16* sb = zb + (size_t)(c & 1) * 8388608;
            ZLD(xwA, sb, 0); ZLD(xwB, sb, 1); ZLD(xwC, sb, 2); ZLD(xwD, sb, 3);
            for (int i = 0; i < 32; i += 4) {
                STEP(xwA, i);
                STEP(xwB, i + 1);
                STEP(xwC, i + 2);
                STEP(xwD, i + 3);
            }
            if (tid == 0) atomicAdd(cdone + c, 1u);
        }
#undef STEP
#undef ZLD
        #pragma unroll
        for (int r2 = 0; r2 < 2; ++r2) {
            int b = qgrp * 4 + rlo + r2;
            int unit = cw * 32 + sub * 16 + l16;
            hfin[((size_t)d * B_ + b) * H_ + unit] = h2[r2];
        }
    } else {
        // ================= producer + DVFS heater =================
        const int pid = bid - 64;        // 0..191
        const int w8 = tid >> 6, ph = w8 >> 2, w4 = w8 & 3;
        // heater state: junk fp16 operands from wp, 4 independent MFMA chains
        h8 ha  = *(const h8*)(wp + (size_t)(tid & 1023) * 8);
        h8 hb2 = *(const h8*)(wp + 8192 + (size_t)(tid & 1023) * 8);
        f4 hacc0 = {0.f,0.f,0.f,0.f}, hacc1 = hacc0, hacc2 = hacc0, hacc3 = hacc0;

        // Heat until *FPTR >= 64: check first (fast path), then burn ~1024
        // MFMA (~2-7 µs) per re-check. One wave polls; LDS flag broadcasts.
#define HEAT_UNTIL(FPTR)                                                          \
        {                                                                         \
            if (tid == 0) hflag = 0;                                              \
            __syncthreads();                                                      \
            while (true) {                                                        \
                if (tid == 0) {                                                   \
                    unsigned hv;                                                  \
                    asm volatile("global_load_dword %0, %1, off sc0 sc1"          \
                                 : "=v"(hv) : "v"(FPTR) : "memory");              \
                    asm volatile("s_waitcnt vmcnt(0)" : "+v"(hv) :: "memory");    \
                    if (hv >= 64u) hflag = 1;                                     \
                }                                                                 \
                __syncthreads();                                                  \
                if (hflag) break;                                                 \
                _Pragma("unroll 1")                                               \
                for (int hit = 0; hit < 256; ++hit) {                             \
                    hacc0 = __builtin_amdgcn_mfma_f32_16x16x32_f16(ha, hb2, hacc0, 0, 0, 0); \
                    hacc1 = __builtin_amdgcn_mfma_f32_16x16x32_f16(ha, hb2, hacc1, 0, 0, 0); \
                    hacc2 = __builtin_amdgcn_mfma_f32_16x16x32_f16(ha, hb2, hacc2, 0, 0, 0); \
                    hacc3 = __builtin_amdgcn_mfma_f32_16x16x32_f16(ha, hb2, hacc3, 0, 0, 0); \
                }                                                                 \
            }                                                                     \
        }

        for (int j = pid; j < 1024; j += 192) {
            const int c = j >> 6, t = j & 63;
            const int sl = t >> 1, d = t & 1;
            const int s = c * 32 + sl;
            if (c >= 2)
                HEAT_UNTIL(cdone + (c - 2));      // slot-reuse gate, heated
            __syncthreads();
            const int tt = d ? (T_ - 1 - s) : s;
            if (tid < B_) rows[tid] = tok[(size_t)tid * T_ + tt];
            __syncthreads();
            for (int it = 0; it < 8; ++it) {
                int pair = it * 8 + w8;      // pair = g8*8 + kb
                int g8 = pair >> 3, kb = pair & 7;
                int b = g8 * 16 + l16;
                int e = kb * 32 + q * 8;
                const float* src = emb + (size_t)rows[b] * E_ + e;
                float4 a = *(const float4*)src;
                float4 cc = *(const float4*)(src + 4);
                h8 hv;
                hv[0] = (_Float16)a.x;  hv[1] = (_Float16)a.y;  hv[2] = (_Float16)a.z;  hv[3] = (_Float16)a.w;
                hv[4] = (_Float16)cc.x; hv[5] = (_Float16)cc.y; hv[6] = (_Float16)cc.z; hv[7] = (_Float16)cc.w;
                xle[pair * 64 + lane] = hv;
            }
            __syncthreads();
            const float* bias = d ? bb : bf;
            _Float16* zslot = zbuf + (size_t)(c & 1) * 8388608;
            for (int pi = 0; pi < 2; ++pi) {
                const int p = ph * 2 + pi;
                const _Float16* bx = wp + (size_t)(d * 32 + p * 4 + w4) * 16384;
                h8 wb[4][8];
                #pragma unroll
                for (int nt = 0; nt < 4; ++nt)
                    #pragma unroll
                    for (int kb = 0; kb < 8; ++kb)
                        wb[nt][kb] = *(const h8*)(bx + nt * 4096 + l16 * 256 + kb * 32 + q * 8);
                float bvv[4];
                #pragma unroll
                for (int nt = 0; nt < 4; ++nt)
                    bvv[nt] = bias[nt * 256 + p * 64 + w4 * 16 + l16];
                for (int g8 = 0; g8 < 8; ++g8) {
                    h8 xa[8];
                    #pragma unroll
                    for (int kb = 0; kb < 8; ++kb)
                        xa[kb] = xle[(g8 * 8 + kb) * 64 + lane];
                    f4 acc[4];
                    #pragma unroll
                    for (int nt = 0; nt < 4; ++nt)
                        acc[nt] = (f4){bvv[nt], bvv[nt], bvv[nt], bvv[nt]};
                    #pragma unroll
                    for (int kb = 0; kb < 8; ++kb)
                        #pragma unroll
                        for (int nt = 0; nt < 4; ++nt)
                            acc[nt] = __builtin_amdgcn_mfma_f32_16x16x32_f16(xa[kb], wb[nt][kb], acc[nt], 0, 0, 0);
                    size_t base = (((size_t)(sl * 2 + d) * 32 + (g8 * 4 + q)) * 8
                                   + (p * 2 + (w4 >> 1))) * 64;
                    #pragma unroll
                    for (int k = 0; k < 2; ++k) {
                        u4 pk;
                        #pragma unroll
                        for (int g = 0; g < 4; ++g) {
                            _Float16 e0 = (_Float16)acc[g][2 * k];
                            _Float16 e1 = (_Float16)acc[g][2 * k + 1];
                            pk[g] = (unsigned)__builtin_bit_cast(unsigned short, e0)
                                  | ((unsigned)__builtin_bit_cast(unsigned short, e1) << 16);
                        }
                        _Float16* da = zslot + (base + ((w4 & 1) * 2 + k) * 16 + l16) * 8;
                        asm volatile("global_store_dwordx4 %0, %1, off sc0 sc1" :: "v"(da), "v"(pk) : "memory");
                    }
                }
            }
            asm volatile("s_waitcnt vmcnt(0)" ::: "memory");
            __syncthreads();               // all 8 waves' stores issued+acked
            if (tid == 0) {
                __threadfence();           // RELEASE
                atomicAdd(pdone + c, 1u);
            }
        }
        // all tiles produced: heat until every consumer finished chunk 15
        HEAT_UNTIL(cdone + 15);
#undef HEAT_UNTIL
        // keep the heater chains alive (rule #17: no DCE of the burn loops)
        asm volatile("" :: "v"(hacc0), "v"(hacc1), "v"(hacc2), "v"(hacc3));
    }
}

// K4: head (proven, unchanged).
__global__ __launch_bounds__(256) void k_head(const float* __restrict__ hfin,
        const float* __restrict__ W1, const float* __restrict__ b1,
        const float* __restrict__ W2, const float* __restrict__ b2, float* __restrict__ out)
{
    const int b = blockIdx.x;
    const int tid = threadIdx.x;
    __shared__ float hcat[2 * H_];
    __shared__ float a1[256];
    if (tid < 128) {
        if (tid < 64)
            ((float4*)hcat)[tid] = ((const float4*)(hfin + (size_t)b * H_))[tid];
        else
            ((float4*)(hcat + H_))[tid - 64] = ((const float4*)(hfin + (size_t)(B_ + b) * H_))[tid - 64];
    }
    __syncthreads();
    {
        float s = b1[tid];
        #pragma unroll 4
        for (int k = 0; k < 2 * H_; ++k)
            s += hcat[k] * W1[(size_t)k * 256 + tid];
        a1[tid] = s > 0.f ? s : 0.f;
    }
    __syncthreads();
    if (tid < 32) {
        float s = b2[tid];
        #pragma unroll 4
        for (int j = 0; j < 256; ++j)
            s += a1[j] * W2[(size_t)j * 32 + tid];
        float mx = s;
        #pragma unroll
        for (int o = 16; o > 0; o >>= 1)
            mx = fmaxf(mx, __shfl_xor(mx, o, 32));
        float e = __expf(s - mx);
        float sum = e;
        #pragma unroll
        for (int o = 16; o > 0; o >>= 1)
            sum += __shfl_xor(sum, o, 32);
        out[(size_t)b * 32 + tid] = e / sum;
    }
}

// ---------------------------------------------------------------------------
extern "C" void kernel_launch(void* const* d_in, const int* in_sizes, int n_in,
                              void* d_out, int out_size, void* d_ws, size_t ws_size,
                              hipStream_t stream)
{
    (void)in_sizes; (void)n_in; (void)out_size; (void)ws_size;
    const int*   tok = (const int*)d_in[0];
    const float* emb = (const float*)d_in[1];
    const float* Wf  = (const float*)d_in[2];
    const float* Uf  = (const float*)d_in[3];
    const float* bf  = (const float*)d_in[4];
    const float* Wb  = (const float*)d_in[5];
    const float* Ub  = (const float*)d_in[6];
    const float* bb  = (const float*)d_in[7];
    const float* W1  = (const float*)d_in[8];
    const float* b1  = (const float*)d_in[9];
    const float* W2  = (const float*)d_in[10];
    const float* b2  = (const float*)d_in[11];
    float* out = (float*)d_out;

    char* ws = (char*)d_ws;
    _Float16* wp    = (_Float16*)(ws);               //  2,097,152 B
    char*     uqp   = (char*)    (ws + 2097152);     //    524,288 B
    float*    scl   = (float*)   (ws + 2621440);     //      8,192 B
    float*    hfin  = (float*)   (ws + 2629632);     //    262,144 B
    unsigned* flags = (unsigned*)(ws + 2891776);     //        256 B
    _Float16* zbuf  = (_Float16*)(ws + 4194304);     // 33,554,432 B (2-slot ring)

    k_perm <<<64, 256, 0, stream>>>(Wf, Uf, Wb, Ub, wp);
    k_permU<<<16, 256, 0, stream>>>(Uf, Ub, uqp, scl);
    // flags MUST be zeroed every launch (stale counters bit-match next iter).
    hipMemsetAsync(flags, 0, 256, stream);
    k_fused<<<256, 512, 0, stream>>>(tok, emb, wp, uqp, scl, bf, bb,
                                     zbuf, flags, flags + 16, hfin);
    k_head <<<B_, 256, 0, stream>>>(hfin, W1, b1, W2, b2, out);
}

// Round 11
// 1575.522 us; speedup vs baseline: 16.3291x; 1.4469x over previous
//
#include <hip/hip_runtime.h>
#include <hip/hip_fp16.h>

#define T_ 512
#define B_ 128
#define E_ 256
#define H_ 256

typedef _Float16 h8 __attribute__((ext_vector_type(8)));
typedef _Float16 h4 __attribute__((ext_vector_type(4)));
typedef float    f4 __attribute__((ext_vector_type(4)));
typedef unsigned u4 __attribute__((ext_vector_type(4)));
typedef int      i4 __attribute__((ext_vector_type(4)));

// ---------------------------------------------------------------------------
// v11 = R3 (best proven: 2073 µs total, absmax 2.44e-4) + two cycle cuts:
//  (a) raw lgkm-only barrier in k_rnn (R3's __syncthreads drained the counted
//      z prefetch to vmcnt(0) every step — ~300cy/step of exposed L3 latency)
//  (b) branchless 4/5-op sigmoid/tanh (was 8/9 ops with abs+select)
// Session constants (R9/R10 probes): clock capped ~0.79 GHz; R3's step is
// VALU-issue-bound at 2450cy — cuts pay ~1:1 in this structure.
// workspace: wp 0..2M | uq 2M.. | scl | hstate | hfin | zbuf 4M+CT*512KB
// ws_size >= 71.3MB proven (R3 ran CT=128).
// ---------------------------------------------------------------------------

// K2: fp16 W/U B-fragment permute (proven, unchanged).
__global__ __launch_bounds__(256) void k_perm(const float* __restrict__ Wf, const float* __restrict__ Uf,
        const float* __restrict__ Wb, const float* __restrict__ Ub, _Float16* __restrict__ wp)
{
    const int bid = blockIdx.x;
    const int d = bid >> 5, mat = (bid >> 4) & 1, p = (bid >> 2) & 3, w = bid & 3;
    const float* src = d ? (mat ? Ub : Wb) : (mat ? Uf : Wf);
    _Float16* dst = wp + (size_t)bid * 16384;
    const int tid = threadIdx.x;
    const int cbase = p * 64 + w * 16;
    __shared__ float S[256][17];
    for (int nt = 0; nt < 4; ++nt) {
        for (int it = 0; it < 16; ++it) {
            int idx = it * 256 + tid;
            int k = idx >> 4, c16 = idx & 15;
            S[k][c16] = src[(size_t)k * 1024 + nt * 256 + cbase + c16];
        }
        __syncthreads();
        for (int it = 0; it < 16; ++it) {
            int idx = it * 256 + tid;
            int k = idx & 255, c16 = idx >> 8;
            dst[(size_t)nt * 4096 + c16 * 256 + k] = (_Float16)S[k][c16];
        }
        __syncthreads();
    }
}

// K2b: per-column int8 quantization of U (proven, unchanged — 8-wave layout).
__global__ __launch_bounds__(256) void k_permU(const float* __restrict__ Uf,
        const float* __restrict__ Ub, char* __restrict__ uq, float* __restrict__ scl)
{
    const int bid = blockIdx.x;          // d*8 + cw
    const int d = bid >> 3, cw = bid & 7;
    const float* U = d ? Ub : Uf;
    const int tid = threadIdx.x;
    if (tid >= 128) return;
    const int nt = tid >> 4, n = tid & 15;
    const int g = nt >> 1, sub = nt & 1;
    const int col = g * 256 + cw * 32 + sub * 16 + n;
    float mx = 0.f;
    for (int k = 0; k < H_; ++k)
        mx = fmaxf(mx, fabsf(U[(size_t)k * 1024 + col]));
    float su = mx > 0.f ? mx * (1.f / 127.f) : 1.f;
    scl[bid * 128 + tid] = su * (1.f / 127.f);
    float inv = 1.f / su;
    char* dst = uq + (size_t)bid * 32768;
    for (int k = 0; k < H_; ++k) {
        float v = U[(size_t)k * 1024 + col] * inv;
        int qv = (int)__builtin_rintf(v);
        qv = qv > 127 ? 127 : (qv < -127 ? -127 : qv);
        dst[(size_t)((nt * 4 + (k >> 6)) * 64 + ((k >> 4) & 3) * 16 + n) * 16 + (k & 15)] = (char)qv;
    }
}

// ---------------------------------------------------------------------------
// K3a: z = x@W + b GEMM (proven R3 version, unchanged). One block per (sl,d).
// ---------------------------------------------------------------------------
__global__ __launch_bounds__(256) void k_xw(const int* __restrict__ tok,
        const float* __restrict__ emb, const _Float16* __restrict__ wp,
        const float* __restrict__ bf, const float* __restrict__ bb,
        _Float16* __restrict__ xwbuf, int s0)
{
    const int bid = blockIdx.x;
    const int sl = bid >> 1, d = bid & 1;
    const int s = s0 + sl;
    const int tid = threadIdx.x;
    const int w = tid >> 6, lane = tid & 63;
    const int l16 = lane & 15, q = lane >> 4;
    __shared__ int rows[B_];
    __shared__ h8 xle[64 * 64];
    const int t = d ? (T_ - 1 - s) : s;
    if (tid < B_) rows[tid] = tok[(size_t)tid * T_ + t];
    __syncthreads();
    for (int it = 0; it < 16; ++it) {
        int pair = it * 4 + w;           // pair = g8*8 + kb
        int g8 = pair >> 3, kb = pair & 7;
        int b = g8 * 16 + l16;
        int e = kb * 32 + q * 8;
        const float* src = emb + (size_t)rows[b] * E_ + e;
        float4 a = *(const float4*)src;
        float4 c = *(const float4*)(src + 4);
        h8 hv;
        hv[0] = (_Float16)a.x; hv[1] = (_Float16)a.y; hv[2] = (_Float16)a.z; hv[3] = (_Float16)a.w;
        hv[4] = (_Float16)c.x; hv[5] = (_Float16)c.y; hv[6] = (_Float16)c.z; hv[7] = (_Float16)c.w;
        xle[pair * 64 + lane] = hv;
    }
    __syncthreads();
    const float* bias = d ? bb : bf;
    for (int p = 0; p < 4; ++p) {
        const _Float16* bx = wp + (size_t)(d * 32 + p * 4 + w) * 16384;
        h8 wb[4][8];
        #pragma unroll
        for (int nt = 0; nt < 4; ++nt)
            #pragma unroll
            for (int kb = 0; kb < 8; ++kb)
                wb[nt][kb] = *(const h8*)(bx + nt * 4096 + l16 * 256 + kb * 32 + q * 8);
        float bvv[4];
        #pragma unroll
        for (int nt = 0; nt < 4; ++nt)
            bvv[nt] = bias[nt * 256 + p * 64 + w * 16 + l16];
        for (int g8 = 0; g8 < 8; ++g8) {
            h8 xa[8];
            #pragma unroll
            for (int kb = 0; kb < 8; ++kb)
                xa[kb] = xle[(g8 * 8 + kb) * 64 + lane];
            f4 acc[4];
            #pragma unroll
            for (int nt = 0; nt < 4; ++nt)
                acc[nt] = (f4){bvv[nt], bvv[nt], bvv[nt], bvv[nt]};
            #pragma unroll
            for (int kb = 0; kb < 8; ++kb)
                #pragma unroll
                for (int nt = 0; nt < 4; ++nt)
                    acc[nt] = __builtin_amdgcn_mfma_f32_16x16x32_f16(xa[kb], wb[nt][kb], acc[nt], 0, 0, 0);
            _Float16* dst = xwbuf + (((size_t)sl * 2 + d) * 8 + g8) * 16384
                          + (size_t)(p * 2 + (w >> 1)) * 2048 + (size_t)lane * 32 + (w & 1) * 4;
            #pragma unroll
            for (int nt = 0; nt < 4; ++nt) {
                h4 v = { (_Float16)acc[nt][0], (_Float16)acc[nt][1],
                         (_Float16)acc[nt][2], (_Float16)acc[nt][3] };
                *(h4*)(dst + nt * 8) = v;
            }
        }
    }
}

// ---------------------------------------------------------------------------
// K3b: recurrence (R3 structure: 16 WGs x 512thr, 8 waves, U-i8 in VGPRs,
// LDS h-exchange, 2-deep z prefetch). v11 cuts: raw lgkm-barrier (keeps the
// counted vmcnt(4) honest), branchless 4/5-op sigmoid/tanh.
// ---------------------------------------------------------------------------
__device__ __forceinline__ float fsig(float x) {
    // rcp(1+e^-x): x<<0 -> exp->+inf -> rcp->0; x>>0 -> exp->0 -> 1. Branchless.
    return __builtin_amdgcn_rcpf(1.0f + __expf(-x));
}
__device__ __forceinline__ float ftanh(float x) {
    return __builtin_fmaf(2.0f, __builtin_amdgcn_rcpf(1.0f + __expf(-2.0f * x)), -1.0f);
}

#define XLD(D, P, OFF) asm volatile("global_load_dwordx4 %0, %1, off offset:" OFF \
    : "=v"(D) : "v"(P) : "memory")

__global__ __launch_bounds__(512, 2) void k_rnn(
        const _Float16* __restrict__ xwbuf, const char* __restrict__ uq,
        const float* __restrict__ scl, float* __restrict__ hstate,
        float* __restrict__ hfin, int s0, int nsteps)
{
    const int bid = blockIdx.x;          // d*8 + grp
    const int d = bid >> 3, grp = bid & 7;
    const int tid = threadIdx.x;
    const int cw = tid >> 6, lane = tid & 63;
    const int l16 = lane & 15, q = lane >> 4;

    __shared__ char hbuf[2][4096];       // [parity][row 16][unit-chunk^row 16][16B]

    i4 uw[8][4];
    {
        const char* ub = uq + (size_t)(d * 8 + cw) * 32768;
        #pragma unroll
        for (int nt = 0; nt < 8; ++nt)
            #pragma unroll
            for (int kb = 0; kb < 4; ++kb)
                uw[nt][kb] = *(const i4*)(ub + (size_t)((nt * 4 + kb) * 64 + lane) * 16);
        #pragma unroll
        for (int nt = 0; nt < 8; ++nt)
            #pragma unroll
            for (int kb = 0; kb < 4; ++kb)
                asm volatile("" : "+v"(uw[nt][kb]));
    }
    float sclv[8];
    #pragma unroll
    for (int nt = 0; nt < 8; ++nt)
        sclv[nt] = scl[(d * 8 + cw) * 128 + nt * 16 + l16];

    float c8[8], hh8[8];
    if (s0 == 0) {
        #pragma unroll
        for (int j = 0; j < 8; ++j) { c8[j] = 0.f; hh8[j] = 0.f; }
    } else {
        const float* st = hstate + ((size_t)(bid * 8 + cw) * 64 + lane) * 16;
        #pragma unroll
        for (int j = 0; j < 8; ++j) { c8[j] = st[j]; hh8[j] = st[8 + j]; }
        char* hb = hbuf[(s0 - 1) & 1];   // rebuild h_{s0-1} exchange tile
        #pragma unroll
        for (int sub = 0; sub < 2; ++sub)
            #pragma unroll
            for (int r = 0; r < 4; ++r) {
                int j = sub * 4 + r;
                int hq = (int)__builtin_rintf(hh8[j] * 127.f);
                int row = q * 4 + r;
                hb[row * 256 + (((cw * 2 + sub) ^ row) << 4) + l16] = (char)hq;
            }
    }
    __syncthreads();                      // full barrier once, outside the loop

    const int NS = nsteps;
    const _Float16* xbase = xwbuf + ((size_t)d * 8 + grp) * 16384
                          + (size_t)cw * 2048 + (size_t)lane * 32;
    u4 xwA[4], xwB[4];
    {
        const _Float16* pp = xbase;
        XLD(xwA[0], pp, "0"); XLD(xwA[1], pp, "16"); XLD(xwA[2], pp, "32"); XLD(xwA[3], pp, "48");
        const _Float16* p2 = xbase + 262144;
        XLD(xwB[0], p2, "0"); XLD(xwB[1], p2, "16"); XLD(xwB[2], p2, "32"); XLD(xwB[3], p2, "48");
    }

#define STEP(XW, I, VM)                                                          \
    {                                                                            \
        const int s_ = s0 + (I);                                                 \
        i4 acc[8];                                                               \
        _Pragma("unroll")                                                        \
        for (int nt = 0; nt < 8; ++nt) acc[nt] = (i4){0, 0, 0, 0};               \
        if (s_ > 0) {                                                            \
            const char* hb = hbuf[(s_ - 1) & 1];                                 \
            i4 hf[4];                                                            \
            _Pragma("unroll")                                                    \
            for (int kb = 0; kb < 4; ++kb)                                       \
                hf[kb] = *(const i4*)(hb + l16 * 256 + (((kb * 4 + q) ^ l16) << 4)); \
            _Pragma("unroll")                                                    \
            for (int kb = 0; kb < 4; ++kb)                                       \
                _Pragma("unroll")                                                \
                for (int nt = 0; nt < 8; ++nt)                                   \
                    acc[nt] = __builtin_amdgcn_mfma_i32_16x16x64_i8(hf[kb], uw[nt][kb], acc[nt], 0, 0, 0); \
        }                                                                        \
        asm volatile("s_waitcnt " VM                                             \
            : "+v"(XW[0]), "+v"(XW[1]), "+v"(XW[2]), "+v"(XW[3]) :: "memory");   \
        h8 xh[4];                                                                \
        _Pragma("unroll")                                                        \
        for (int jj = 0; jj < 4; ++jj) xh[jj] = __builtin_bit_cast(h8, XW[jj]);  \
        if ((I) + 2 < NS) {                                                      \
            const _Float16* pp = xbase + (size_t)((I) + 2) * 262144;             \
            XLD(XW[0], pp, "0"); XLD(XW[1], pp, "16");                           \
            XLD(XW[2], pp, "32"); XLD(XW[3], pp, "48");                          \
        }                                                                        \
        char* hbw = hbuf[s_ & 1];                                                \
        _Pragma("unroll")                                                        \
        for (int sub = 0; sub < 2; ++sub)                                        \
            _Pragma("unroll")                                                    \
            for (int r = 0; r < 4; ++r) {                                        \
                const int j = sub * 4 + r;                                       \
                float zi = (float)acc[sub][r]     * sclv[sub]     + (float)xh[0][j]; \
                float zf = (float)acc[2 + sub][r] * sclv[2 + sub] + (float)xh[1][j]; \
                float zg = (float)acc[4 + sub][r] * sclv[4 + sub] + (float)xh[2][j]; \
                float zo = (float)acc[6 + sub][r] * sclv[6 + sub] + (float)xh[3][j]; \
                float cn = fsig(zf) * c8[j] + fsig(zi) * ftanh(zg);              \
                c8[j] = cn;                                                      \
                float hv = fsig(zo) * ftanh(cn);                                 \
                hh8[j] = hv;                                                     \
                int hq = (int)__builtin_rintf(hv * 127.f);                       \
                const int row = q * 4 + r;                                       \
                hbw[row * 256 + (((cw * 2 + sub) ^ row) << 4) + l16] = (char)hq; \
            }                                                                    \
        asm volatile("s_waitcnt lgkmcnt(0)\n\ts_barrier" ::: "memory");          \
    }

    for (int i = 0; i < NS - 2; i += 2) {
        STEP(xwA, i, "vmcnt(4)");
        STEP(xwB, i + 1, "vmcnt(4)");
    }
    STEP(xwA, NS - 2, "vmcnt(4)");
    STEP(xwB, NS - 1, "vmcnt(0)");
#undef STEP

    if (s0 + NS == T_) {
        #pragma unroll
        for (int sub = 0; sub < 2; ++sub)
            #pragma unroll
            for (int r = 0; r < 4; ++r)
                hfin[((size_t)d * B_ + grp * 16 + q * 4 + r) * H_ + cw * 32 + sub * 16 + l16]
                    = hh8[sub * 4 + r];
    } else {
        float* st = hstate + ((size_t)(bid * 8 + cw) * 64 + lane) * 16;
        #pragma unroll
        for (int j = 0; j < 8; ++j) { st[j] = c8[j]; st[8 + j] = hh8[j]; }
    }
}

// K4: head (proven, unchanged).
__global__ __launch_bounds__(256) void k_head(const float* __restrict__ hfin,
        const float* __restrict__ W1, const float* __restrict__ b1,
        const float* __restrict__ W2, const float* __restrict__ b2, float* __restrict__ out)
{
    const int b = blockIdx.x;
    const int tid = threadIdx.x;
    __shared__ float hcat[2 * H_];
    __shared__ float a1[256];
    if (tid < 128) {
        if (tid < 64)
            ((float4*)hcat)[tid] = ((const float4*)(hfin + (size_t)b * H_))[tid];
        else
            ((float4*)(hcat + H_))[tid - 64] = ((const float4*)(hfin + (size_t)(B_ + b) * H_))[tid - 64];
    }
    __syncthreads();
    {
        float s = b1[tid];
        #pragma unroll 4
        for (int k = 0; k < 2 * H_; ++k)
            s += hcat[k] * W1[(size_t)k * 256 + tid];
        a1[tid] = s > 0.f ? s : 0.f;
    }
    __syncthreads();
    if (tid < 32) {
        float s = b2[tid];
        #pragma unroll 4
        for (int j = 0; j < 256; ++j)
            s += a1[j] * W2[(size_t)j * 32 + tid];
        float mx = s;
        #pragma unroll
        for (int o = 16; o > 0; o >>= 1)
            mx = fmaxf(mx, __shfl_xor(mx, o, 32));
        float e = __expf(s - mx);
        float sum = e;
        #pragma unroll
        for (int o = 16; o > 0; o >>= 1)
            sum += __shfl_xor(sum, o, 32);
        out[(size_t)b * 32 + tid] = e / sum;
    }
}

// ---------------------------------------------------------------------------
extern "C" void kernel_launch(void* const* d_in, const int* in_sizes, int n_in,
                              void* d_out, int out_size, void* d_ws, size_t ws_size,
                              hipStream_t stream)
{
    (void)in_sizes; (void)n_in; (void)out_size;
    const int*   tok = (const int*)d_in[0];
    const float* emb = (const float*)d_in[1];
    const float* Wf  = (const float*)d_in[2];
    const float* Uf  = (const float*)d_in[3];
    const float* bf  = (const float*)d_in[4];
    const float* Wb  = (const float*)d_in[5];
    const float* Ub  = (const float*)d_in[6];
    const float* bb  = (const float*)d_in[7];
    const float* W1  = (const float*)d_in[8];
    const float* b1  = (const float*)d_in[9];
    const float* W2  = (const float*)d_in[10];
    const float* b2  = (const float*)d_in[11];
    float* out = (float*)d_out;

    char* ws = (char*)d_ws;
    _Float16* wp   = (_Float16*)(ws);                // 2,097,152 B
    char*     uqp  = (char*)    (ws + 2097152);      //   524,288 B
    float*    scl  = (float*)   (ws + 2621440);      //     8,192 B
    float*    hst  = (float*)   (ws + 2629632);      //   524,288 B
    float*    hfin = (float*)   (ws + 3153920);      //   262,144 B
    _Float16* xwb  = (_Float16*)(ws + 4194304);      // CT * 524,288 B

    // chunk the time axis so xwbuf fits the workspace (>=71.3MB proven: R3
    // ran CT=128; larger rungs only if the workspace actually allows).
    size_t avail = ws_size > 4194304 ? ws_size - 4194304 : 0;
    int CT = 32;
    if      (avail >= (size_t)512 * 524288) CT = 512;
    else if (avail >= (size_t)256 * 524288) CT = 256;
    else if (avail >= (size_t)128 * 524288) CT = 128;
    else if (avail >= (size_t) 64 * 524288) CT = 64;

    k_perm <<<64, 256, 0, stream>>>(Wf, Uf, Wb, Ub, wp);
    k_permU<<<16, 256, 0, stream>>>(Uf, Ub, uqp, scl);
    for (int s0 = 0; s0 < T_; s0 += CT) {
        k_xw <<<CT * 2, 256, 0, stream>>>(tok, emb, wp, bf, bb, xwb, s0);
        k_rnn<<<16, 512, 0, stream>>>(xwb, uqp, scl, hst, hfin, s0, CT);
    }
    k_head<<<B_, 256, 0, stream>>>(hfin, W1, b1, W2, b2, out);
}